// Round 16
// baseline (176.913 us; speedup 1.0000x reference)
//
#include <hip/hip_runtime.h>
#include <stdint.h>

typedef _Float16 f16;
typedef _Float16 half4 __attribute__((ext_vector_type(4)));
typedef _Float16 half8 __attribute__((ext_vector_type(8)));
typedef float f32x4 __attribute__((ext_vector_type(4)));

#define BATCH 16
#define NQ 64
#define SL 4096
#define DH 128

// Tiled f16 layout for Kt/Vt, per b (halves):
//   off(d, n) = (n>>5)*4096 + (d>>4)*512 + ((n>>3)&3)*128 + (d&15)*8 + (n&7)
// A fragment read (16x16x32 MFMA) is then a coalesced global read base+l*16.

// ---------------------------------------------------------------------------
// Kernel P: convert f32 [b][n][d] -> f16 tiled [b][(d,n) tiled]
// ---------------------------------------------------------------------------
__global__ __launch_bounds__(256) void kprep(const float* __restrict__ Kg,
                                             const float* __restrict__ Vg,
                                             f16* __restrict__ Kt,
                                             f16* __restrict__ Vt) {
  __shared__ f16 Ld[128][130];
  const int blk = blockIdx.x;
  const int b = blk >> 6;
  const int tensor = (blk >> 5) & 1;
  const int chunk = blk & 31;
  const float* src = tensor ? Vg : Kg;
  f16* dst = tensor ? Vt : Kt;
  const int t = threadIdx.x;
  const int n0 = chunk * 128;
  {
    const int d = t & 127;
    const int nl = t >> 7;  // 0..1
    const float* s = src + ((size_t)b * SL + n0 + nl) * DH + d;
    for (int it = 0; it < 64; ++it)
      Ld[d][nl + it * 2] = (f16)s[(size_t)it * 2 * DH];
  }
  __syncthreads();
  {
    const int r = t & 15;
    const int kc = (t >> 4) & 3;
    const int w = t >> 6;
    char* dstb = (char*)(dst + (size_t)b * DH * SL);
#pragma unroll
    for (int tl = 0; tl < 4; ++tl)
#pragma unroll
      for (int hh = 0; hh < 2; ++hh) {
        const int dhi = w + hh * 4;
        const int d = dhi * 16 + r;
        const int nl = tl * 32 + kc * 8;
        const half8 v = *(const half8*)&Ld[d][nl];
        *(half8*)(dstb + (size_t)(chunk * 4 + tl) * 8192 + dhi * 1024 +
                  kc * 256 + r * 16) = v;
      }
  }
}

// ---------------------------------------------------------------------------
// Kernel S: E[b][q][n] = (f16)exp(scale * Q.K[n]).  Reads tiled Kt.
// Also writes denomp[ns][b][q] = sum_{n in quarter} E  (deterministic).
// ---------------------------------------------------------------------------
__global__ __launch_bounds__(256) void kscore(const float* __restrict__ Q,
                                              const f16* __restrict__ Kt,
                                              f16* __restrict__ E,
                                              float* __restrict__ denomp) {
  const int blk = (blockIdx.x & 7) * 64 + (blockIdx.x >> 3);
  __shared__ float Qs[8][128];
  __shared__ float wsum[4][4];
  const int b = blk >> 5;
  const int qg = (blk >> 2) & 7;
  const int ns = blk & 3;
  const int t = threadIdx.x;
  for (int i = t; i < 8 * 128; i += 256)
    Qs[i >> 7][i & 127] = Q[((size_t)b * NQ + qg * 8 + (i >> 7)) * DH + (i & 127)];
  __syncthreads();
  const int w = t >> 6, l = t & 63;
  const int q0 = (w >> 1) * 4;
  const int nbase = ns * 1024 + (w & 1) * 512 + l * 8;
  const f16* kb = Kt + (size_t)b * DH * SL + (size_t)(nbase >> 5) * 4096 +
                  (size_t)((nbase >> 3) & 3) * 128;
  float acc[4][8] = {};
  for (int d = 0; d < DH; ++d) {
    const half8 kv = *(const half8*)(kb + (d >> 4) * 512 + (d & 15) * 8);
    float kf[8];
#pragma unroll
    for (int j = 0; j < 8; ++j) kf[j] = (float)kv[j];
#pragma unroll
    for (int qi = 0; qi < 4; ++qi) {
      const float qv = Qs[q0 + qi][d];
#pragma unroll
      for (int j = 0; j < 8; ++j) acc[qi][j] += qv * kf[j];
    }
  }
  const float scl = 0.08838834764831845f;  // 1/sqrt(128)
#pragma unroll
  for (int qi = 0; qi < 4; ++qi) {
    half8 ev;
    float ds = 0.f;
#pragma unroll
    for (int j = 0; j < 8; ++j) {
      ev[j] = (f16)__expf(acc[qi][j] * scl);
      ds += (float)ev[j];
    }
    *(half8*)&E[((size_t)b * NQ + qg * 8 + q0 + qi) * SL + nbase] = ev;
    for (int off = 1; off < 64; off <<= 1) ds += __shfl_xor(ds, off);
    if (l == 0) wsum[w][qi] = ds;
  }
  __syncthreads();
  if (t < 8) {
    const int hw = (t >> 2) * 2;
    denomp[(size_t)ns * BATCH * NQ + (size_t)b * NQ + qg * 8 + t] =
        wsum[hw][t & 3] + wsum[hw + 1][t & 3];
  }
}

// ---------------------------------------------------------------------------
// Kernel EVK v2: per (b, n-eighth, qh) block, BOTH tensors:
//   EVp[ne][b][q][v] = sum_{n in eighth} E[q][n]*V[n][v]; same for EK.
// E super-chunk (32q x 128n) staged in padded LDS [32][136] (2-way banks =
// free); b-frags are single ds_read_b128; 2 barriers per 32 MFMAs.
// ---------------------------------------------------------------------------
__global__ __launch_bounds__(256) void kev(const f16* __restrict__ Vt,
                                           const f16* __restrict__ Kt,
                                           const f16* __restrict__ E,
                                           float* __restrict__ EVp,
                                           float* __restrict__ EKp) {
  __shared__ __align__(16) f16 Es[32][136];
  const int blk = (blockIdx.x & 7) * 32 + (blockIdx.x >> 3);  // XCD swizzle
  const int b = blk >> 4;
  const int ne = (blk >> 1) & 7;  // n-eighth (512 n)
  const int qh = blk & 1;         // q-half (32 q)
  const char* vsrc = (const char*)(Vt + (size_t)b * DH * SL);
  const char* ksrc = (const char*)(Kt + (size_t)b * DH * SL);
  const f16* Eb = E + ((size_t)b * NQ + qh * 32) * SL + ne * 512;
  const int t = threadIdx.x, w = t >> 6, l = t & 63;
  const int eq = t >> 3;          // staging q row 0..31
  const int en = (t & 7) * 16;    // staging 16 n per thread

  f32x4 accV[2][2] = {}, accK[2][2] = {};  // [sv2][qsub]

  for (int sc = 0; sc < 4; ++sc) {  // super-chunk = 128 n
    __syncthreads();                // protect previous super-chunk reads
    {
      const f16* ep = Eb + (size_t)eq * SL + sc * 128 + en;
      *(half8*)&Es[eq][en] = *(const half8*)ep;
      *(half8*)&Es[eq][en + 8] = *(const half8*)(ep + 8);
    }
    __syncthreads();
    const int nbase = ne * 512 + sc * 128;
#pragma unroll
    for (int c = 0; c < 4; ++c) {
      const size_t gb = (size_t)((nbase + c * 32) >> 5) * 8192 + l * 16;
      const half8 b0 = *(const half8*)&Es[l & 15][c * 32 + (l >> 4) * 8];
      const half8 b1 = *(const half8*)&Es[16 + (l & 15)][c * 32 + (l >> 4) * 8];
      const half8 av0 = *(const half8*)(vsrc + gb + w * 1024);
      const half8 av1 = *(const half8*)(vsrc + gb + (w + 4) * 1024);
      const half8 ak0 = *(const half8*)(ksrc + gb + w * 1024);
      const half8 ak1 = *(const half8*)(ksrc + gb + (w + 4) * 1024);
      accV[0][0] = __builtin_amdgcn_mfma_f32_16x16x32_f16(av0, b0, accV[0][0], 0, 0, 0);
      accV[0][1] = __builtin_amdgcn_mfma_f32_16x16x32_f16(av0, b1, accV[0][1], 0, 0, 0);
      accV[1][0] = __builtin_amdgcn_mfma_f32_16x16x32_f16(av1, b0, accV[1][0], 0, 0, 0);
      accV[1][1] = __builtin_amdgcn_mfma_f32_16x16x32_f16(av1, b1, accV[1][1], 0, 0, 0);
      accK[0][0] = __builtin_amdgcn_mfma_f32_16x16x32_f16(ak0, b0, accK[0][0], 0, 0, 0);
      accK[0][1] = __builtin_amdgcn_mfma_f32_16x16x32_f16(ak0, b1, accK[0][1], 0, 0, 0);
      accK[1][0] = __builtin_amdgcn_mfma_f32_16x16x32_f16(ak1, b0, accK[1][0], 0, 0, 0);
      accK[1][1] = __builtin_amdgcn_mfma_f32_16x16x32_f16(ak1, b1, accK[1][1], 0, 0, 0);
    }
  }

  float* dstV = EVp + ((size_t)ne * BATCH * NQ + (size_t)b * NQ + qh * 32) * DH;
  float* dstK = EKp + ((size_t)ne * BATCH * NQ + (size_t)b * NQ + qh * 32) * DH;
#pragma unroll
  for (int sv2 = 0; sv2 < 2; ++sv2)
#pragma unroll
    for (int qsub = 0; qsub < 2; ++qsub) {
      const int q = qsub * 16 + (l & 15);
      const int row = (w + sv2 * 4) * 16 + (l >> 4) * 4;
      *(f32x4*)&dstV[(size_t)q * DH + row] = accV[sv2][qsub];
      *(f32x4*)&dstK[(size_t)q * DH + row] = accK[sv2][qsub];
    }
}

// ---------------------------------------------------------------------------
// Kernel G: per (b, 4 q):  T[v][k] = sum_n V[n,v] * (E_n*K[n,k])  via MFMA.
// 512 thr / 8 waves / 1 block per CU, wave 64x32 x 4q; block's E (32KB) in
// LDS (prologue-staged); hot loop = 6 V/K global fragment loads + 32 MFMA,
// no barriers; ping-pong distance 1; setprio.  (Frozen: best of 6 variants.)
// ---------------------------------------------------------------------------
__global__ __launch_bounds__(512, 2) void kjac(
    const f16* __restrict__ Vt, const f16* __restrict__ Kt,
    const f16* __restrict__ E, const float* __restrict__ EV,
    const float* __restrict__ EK, const float* __restrict__ denomp,
    float* __restrict__ out) {
  __shared__ __align__(16) f16 El[4][4096];  // 32KB: E rows q0..q0+3
  const int blk = (blockIdx.x & 7) * 32 + (blockIdx.x >> 3);  // XCD swizzle
  const int b = blk >> 4;
  const int q0 = (blk & 15) * 4;
  const int t = threadIdx.x, w = t >> 6, l = t & 63;
  const int sA = (w >> 2) * 4;  // A row-subtile base (row half: 64 rows)
  const int sB = (w & 3) * 2;   // B col-subtile base (col quarter: 32 cols)
  const char* vtb = (const char*)(Vt + (size_t)b * DH * SL) + sA * 1024 + l * 16;
  const char* ktb = (const char*)(Kt + (size_t)b * DH * SL) + sB * 1024 + l * 16;

  {
    const f16* Eg = E + ((size_t)b * NQ + q0) * SL;
#pragma unroll
    for (int p = 0; p < 4; ++p)
      *(half8*)&El[p][t * 8] = *(const half8*)(Eg + (size_t)p * SL + t * 8);
  }
  __syncthreads();

  f32x4 acc[4][4][2] = {};
  half8 vfA[4], kfA[2], efA[4], vfB[4], kfB[2], efB[4];
  const int eoff = (l >> 4) * 8;

#define LOADF(vf, kf, ef, tile)                                              \
  {                                                                          \
    const size_t gb = (size_t)(tile) * 8192;                                 \
    _Pragma("unroll") for (int i = 0; i < 4; ++i) vf[i] =                    \
        *(const half8*)(vtb + gb + i * 1024);                                \
    _Pragma("unroll") for (int j = 0; j < 2; ++j) kf[j] =                    \
        *(const half8*)(ktb + gb + j * 1024);                                \
    _Pragma("unroll") for (int q = 0; q < 4; ++q) ef[q] =                    \
        *(const half8*)&El[q][(tile) * 32 + eoff];                           \
  }

#define MFMA32(vf, kf, ef)                                                   \
  {                                                                          \
    __builtin_amdgcn_s_setprio(1);                                           \
    _Pragma("unroll") for (int q = 0; q < 4; ++q) {                          \
      const half8 uk0 = ef[q] * kf[0];                                       \
      const half8 uk1 = ef[q] * kf[1];                                       \
      _Pragma("unroll") for (int i = 0; i < 4; ++i) {                        \
        acc[q][i][0] = __builtin_amdgcn_mfma_f32_16x16x32_f16(               \
            vf[i], uk0, acc[q][i][0], 0, 0, 0);                              \
        acc[q][i][1] = __builtin_amdgcn_mfma_f32_16x16x32_f16(               \
            vf[i], uk1, acc[q][i][1], 0, 0, 0);                              \
      }                                                                      \
    }                                                                        \
    __builtin_amdgcn_s_setprio(0);                                           \
  }

  LOADF(vfA, kfA, efA, 0)
  for (int tt = 0; tt < 126; tt += 2) {
    LOADF(vfB, kfB, efB, tt + 1)
    MFMA32(vfA, kfA, efA)
    LOADF(vfA, kfA, efA, tt + 2)
    MFMA32(vfB, kfB, efB)
  }
  LOADF(vfB, kfB, efB, 127)
  MFMA32(vfA, kfA, efA)
  MFMA32(vfB, kfB, efB)
#undef LOADF
#undef MFMA32

  const float scl = 0.08838834764831845f;
  const size_t PS = (size_t)BATCH * NQ * DH;   // partial stride (EV/EK)
  const size_t DS = (size_t)BATCH * NQ;        // partial stride (denom)
#pragma unroll
  for (int q = 0; q < 4; ++q) {
    const size_t qi = (size_t)b * NQ + q0 + q;
    float den = 0.f;
#pragma unroll
    for (int p = 0; p < 4; ++p) den += denomp[p * DS + qi];
    const float invd = 1.0f / den;
    const float* evq = EV + qi * DH;
    const float* ekq = EK + qi * DH;
    float* ob = out + qi * DH * DH;
#pragma unroll
    for (int i = 0; i < 4; ++i) {
      const int row0 = (sA + i) * 16 + (l >> 4) * 4;
      f32x4 ev4 = *(const f32x4*)&evq[row0];
#pragma unroll
      for (int p = 1; p < 8; ++p) ev4 += *(const f32x4*)&evq[p * PS + row0];
#pragma unroll
      for (int j = 0; j < 2; ++j) {
        const int col = (sB + j) * 16 + (l & 15);
        float ek = ekq[col];
#pragma unroll
        for (int p = 1; p < 8; ++p) ek += ekq[p * PS + col];
#pragma unroll
        for (int r = 0; r < 4; ++r)
          ob[(size_t)(row0 + r) * DH + col] =
              scl * invd * (acc[q][i][j][r] - invd * ev4[r] * ek);
      }
    }
  }
}

extern "C" void kernel_launch(void* const* d_in, const int* in_sizes, int n_in,
                              void* d_out, int out_size, void* d_ws,
                              size_t ws_size, hipStream_t stream) {
  const float* Q = (const float*)d_in[0];
  const float* K = (const float*)d_in[1];
  const float* V = (const float*)d_in[2];
  float* out = (float*)d_out;

  // ws: Vt 16.8MB | Kt 16.8MB | E f16 8.4MB | EVp 4MB | EKp 4MB | denomp 16KB
  f16* Vt = (f16*)d_ws;
  f16* Kt = Vt + (size_t)BATCH * DH * SL;
  f16* Ef = Kt + (size_t)BATCH * DH * SL;
  float* EVp = (float*)(Ef + (size_t)BATCH * NQ * SL);
  float* EKp = EVp + 8 * (size_t)BATCH * NQ * DH;
  float* denomp = EKp + 8 * (size_t)BATCH * NQ * DH;

  kprep<<<1024, 256, 0, stream>>>(K, V, Kt, Vt);
  kscore<<<512, 256, 0, stream>>>(Q, Kt, Ef, denomp);
  kev<<<256, 256, 0, stream>>>(Vt, Kt, Ef, EVp, EKp);
  kjac<<<256, 512, 0, stream>>>(Vt, Kt, Ef, EVp, EKp, denomp, out);
}